// Round 7
// baseline (2914.617 us; speedup 1.0000x reference)
//
#include <hip/hip_runtime.h>
#include <hip/hip_bf16.h>

// Team-of-2 LSTM, all-RMW tagged exchange (no flags, no fences, no drains).
// 256 blocks x 512 threads; block i pairs with i^128. Each block holds half
// of W_hh (512 gate rows x 256 K, bf16) in the unified VGPR/AGPR file.
// Cross-block rule (hypothesis R): relaxed agent atomic LOADS can be served
// stale from the local per-XCD L2; atomic RMWs always execute at the
// coherence point. So BOTH sides use RMWs: writer publishes {tag16|bf16}
// words via atomicExch, reader "loads" via fetch_add(+opaque 0). Tags carry
// the handshake; s_sleep backoff bounds retry traffic. Needs ws_size >= 4 MB.

#define TT 256
#define HH 256
#define BC 16

typedef __attribute__((ext_vector_type(8))) short short8;
typedef __attribute__((ext_vector_type(4))) float floatx4;
typedef unsigned long long ull;

__device__ __forceinline__ unsigned short f2bf(float f) {
    union { float f; unsigned u; } v; v.f = f;
    unsigned r = v.u + 0x7FFFu + ((v.u >> 16) & 1u);   // RNE, finite inputs only
    return (unsigned short)(r >> 16);
}
__device__ __forceinline__ float sigf(float x) {
    return __builtin_amdgcn_rcpf(1.f + __expf(-x));
}
__device__ __forceinline__ float tanh_(float x) {
    return 1.f - 2.f * __builtin_amdgcn_rcpf(__expf(2.f * x) + 1.f);
}
// Workgroup barrier that drains only LDS (lgkm), NOT vmcnt: keeps the
// exchange traffic off the critical path. Safe: tag verification, not
// store completion, is the cross-block handshake.
__device__ __forceinline__ void barrier_lds() {
    asm volatile("s_waitcnt lgkmcnt(0)\n\ts_barrier" ::: "memory");
}

__global__ __attribute__((amdgpu_flat_work_group_size(512, 512),
                          amdgpu_waves_per_eu(2, 2)))
void lstm_team2(
    const float* __restrict__ y_hist, const float* __restrict__ h0,
    const float* __restrict__ c0, const float* __restrict__ W_ih,
    const float* __restrict__ W_hh, const float* __restrict__ b_ih,
    const float* __restrict__ b_hh, const float* __restrict__ W_fc,
    const float* __restrict__ b_fc, float* __restrict__ out,
    char* __restrict__ hx)
{
    // h state: [batch 16][hidden 256] bf16, row stride 512B, XOR-swizzled
    __shared__ __align__(16) unsigned short hbuf[2][BC * 256];  // 16 KB
    __shared__ float xbuf[TT * BC];                             // 16 KB
    __shared__ float outacc[BC * 2];

    const int tid = threadIdx.x;
    const int w   = tid >> 6;          // wave 0..7
    const int l   = tid & 63;
    const int lr  = l & 15;            // batch lane (B col / C col)
    const int lg  = l >> 4;            // group 0..3
    const int bid = blockIdx.x;
    const int rho = bid >> 7;          // role 0/1: hidden half
    const int pid = bid ^ 128;         // partner block
    const int b0  = (bid & 127) * BC;  // team batch base
    const int hbase = rho * 128;       // this block's hidden half
    const int u   = hbase + 16 * w + 4 * lg;  // lane's hidden base (4 units)
    const int jj  = tid & 31;          // reader word-quad index
    const int bb  = tid >> 5;          // reader batch

    // ---- stage x: [t][batch] fp32 ----
    for (int idx = tid; idx < TT * BC; idx += 512) {
        int b2 = idx >> 8, t = idx & 255;
        xbuf[t * BC + b2] = y_hist[(size_t)(b0 + b2) * TT + t];
    }
    // ---- stage h0 (full 256 hidden) -> bf16 swizzled LDS buf0 ----
    {
        char* hb = (char*)&hbuf[0][0];
        for (int idx = tid; idx < BC * 128; idx += 512) {
            int b2 = idx >> 7, d = idx & 127;
            const float* hp = &h0[(size_t)(b0 + b2) * HH + 2 * d];
            unsigned val = (unsigned)f2bf(hp[0]) | ((unsigned)f2bf(hp[1]) << 16);
            *(unsigned*)(hb + b2 * 512 + ((d * 4) ^ ((b2 & 7) << 4))) = val;
        }
    }
    if (tid < BC * 2) outacc[tid] = 0.f;

    // ---- per-lane constants ----
    float cc[4];
#pragma unroll
    for (int r = 0; r < 4; ++r)
        cc[r] = c0[(size_t)(b0 + lr) * HH + u + r];

    float wxv[16], biasv[16];
#pragma unroll
    for (int g = 0; g < 4; ++g)
#pragma unroll
        for (int r = 0; r < 4; ++r) {
            int gc = g * 256 + u + r;
            wxv[g * 4 + r]   = W_ih[gc];
            biasv[g * 4 + r] = b_ih[gc] + b_hh[gc];
        }

    // ---- W half -> register-resident bf16 A-fragments ----
    short8 wfrag[32];
    {
        const int wrow = hbase + 16 * w + lr;
        const int cb = 8 * lg;
#pragma unroll
        for (int g = 0; g < 4; ++g)
#pragma unroll
            for (int s = 0; s < 8; ++s) {
                const float* p = &W_hh[(size_t)(g * 256 + wrow) * HH + cb + 32 * s];
                short8 f;
#pragma unroll
                for (int i = 0; i < 8; ++i) f[i] = (short)f2bf(p[i]);
                wfrag[g * 8 + s] = f;
            }
    }
#pragma unroll
    for (int i = 0; i < 32; ++i)
        asm volatile("" : "+v"(wfrag[i]));

    // packet slots: [writer bid][parity] of 8 KB:
    //   u32 word {tag16|bf16} per (batch, hidden_rel): byte = batch*512 + rel*4
    ull* pw[2];
    ull* pr[2];
#pragma unroll
    for (int p = 0; p < 2; ++p) {
        pw[p] = (ull*)(hx + ((size_t)(bid * 2 + p)) * 8192
                          + lr * 512 + 64 * w + 16 * lg);
        pr[p] = (ull*)(hx + ((size_t)(pid * 2 + p)) * 8192
                          + bb * 512 + 16 * jj);
    }

    // Opaque zero: defeats LLVM's idempotent-RMW -> atomic-load rewrite,
    // keeping the reader's fetch_add a real coherence-point RMW.
    ull zero64 = 0;
    asm volatile("" : "+v"(zero64));

    __syncthreads();

    const unsigned sw = (unsigned)((lr & 7) << 4);
    const unsigned rdbase = (unsigned)(lr * 512);
    const unsigned phcol = (unsigned)((1 - rho) * 256);  // partner half byte col
    const unsigned cw = (unsigned)(2 * u);               // own half byte col
    const int sOwn = 4 * rho;                            // own k-range s base
    const int sPar = 4 * (1 - rho);                      // partner k-range s base
    const ull TAGMASK = 0xFFFF0000FFFF0000ULL;
    float hv[4] = {0.f, 0.f, 0.f, 0.f};

#pragma unroll 1
    for (int t = 0; t < TT; ++t) {
        char* rb = (char*)&hbuf[t & 1][0];
        char* wb = (char*)&hbuf[(t + 1) & 1][0];

        float xv = xbuf[t * BC + lr];
        floatx4 acc[4];
#pragma unroll
        for (int g = 0; g < 4; ++g)
#pragma unroll
            for (int r = 0; r < 4; ++r)
                acc[g][r] = fmaf(xv, wxv[g * 4 + r], biasv[g * 4 + r]);

        // ---- own-half MFMAs (data local since last barrier) ----
#pragma unroll
        for (int si = 0; si < 4; ++si) {
            int s = sOwn + si;
            short8 bfr = *(const short8*)(rb + rdbase +
                             (((unsigned)(16 * lg + 64 * s)) ^ sw));
#pragma unroll
            for (int g = 0; g < 4; ++g)
                acc[g] = __builtin_amdgcn_mfma_f32_16x16x32_bf16(
                             wfrag[g * 8 + s], bfr, acc[g], 0, 0, 0);
        }

        // ---- partner half: coherent RMW gather + tag verify ----
        if (t > 0) {
            const ull pat = ((ull)t << 16) | ((ull)t << 48);
            ull* p0 = pr[t & 1];
            ull v0 = __hip_atomic_fetch_add(p0,     zero64, __ATOMIC_RELAXED,
                                            __HIP_MEMORY_SCOPE_AGENT);
            ull v1 = __hip_atomic_fetch_add(p0 + 1, zero64, __ATOMIC_RELAXED,
                                            __HIP_MEMORY_SCOPE_AGENT);
            while (((v0 & TAGMASK) != pat) || ((v1 & TAGMASK) != pat)) {
                __builtin_amdgcn_s_sleep(1);
                v0 = __hip_atomic_fetch_add(p0,     zero64, __ATOMIC_RELAXED,
                                            __HIP_MEMORY_SCOPE_AGENT);
                v1 = __hip_atomic_fetch_add(p0 + 1, zero64, __ATOMIC_RELAXED,
                                            __HIP_MEMORY_SCOPE_AGENT);
            }
            unsigned pa = (unsigned)(v0 & 0xFFFF) |
                          ((unsigned)((v0 >> 32) & 0xFFFF) << 16);
            unsigned pb = (unsigned)(v1 & 0xFFFF) |
                          ((unsigned)((v1 >> 32) & 0xFFFF) << 16);
            uint2 st; st.x = pa; st.y = pb;
            unsigned c = phcol + 8u * (unsigned)jj;
            *(uint2*)(rb + bb * 512 + (c ^ ((unsigned)(bb & 7) << 4))) = st;
            barrier_lds();
        }

        // ---- partner-half MFMAs ----
#pragma unroll
        for (int si = 0; si < 4; ++si) {
            int s = sPar + si;
            short8 bfr = *(const short8*)(rb + rdbase +
                             (((unsigned)(16 * lg + 64 * s)) ^ sw));
#pragma unroll
            for (int g = 0; g < 4; ++g)
                acc[g] = __builtin_amdgcn_mfma_f32_16x16x32_bf16(
                             wfrag[g * 8 + s], bfr, acc[g], 0, 0, 0);
        }

        // ---- gates -> c,h ----
#pragma unroll
        for (int r = 0; r < 4; ++r) {
            float iv = sigf(acc[0][r]);
            float fv = sigf(acc[1][r]);
            float gv = tanh_(acc[2][r]);
            float ov = sigf(acc[3][r]);
            float c2 = fmaf(fv, cc[r], iv * gv);
            cc[r] = c2;
            hv[r] = ov * tanh_(c2);
        }

        // ---- publish own half: {tag|bf16} words via coherence-point RMW ----
        {
            unsigned tg = (unsigned)(t + 1) << 16;
            unsigned w0 = tg | f2bf(hv[0]);
            unsigned w1 = tg | f2bf(hv[1]);
            unsigned w2 = tg | f2bf(hv[2]);
            unsigned w3 = tg | f2bf(hv[3]);
            if (t < TT - 1) {
                ull q0 = (ull)w0 | ((ull)w1 << 32);
                ull q1 = (ull)w2 | ((ull)w3 << 32);
                ull* dst = pw[(t + 1) & 1];
                (void)__hip_atomic_exchange(dst,     q0, __ATOMIC_RELAXED,
                                            __HIP_MEMORY_SCOPE_AGENT);
                (void)__hip_atomic_exchange(dst + 1, q1, __ATOMIC_RELAXED,
                                            __HIP_MEMORY_SCOPE_AGENT);
            }
            // own half -> next LDS buffer
            unsigned lo = (w0 & 0xFFFFu) | (w1 << 16);
            unsigned hi = (w2 & 0xFFFFu) | (w3 << 16);
            uint2 pk; pk.x = lo; pk.y = hi;
            *(uint2*)(wb + rdbase + (cw ^ sw)) = pk;
        }

        barrier_lds();
    }

    // ---- epilogue: partial out = h_T(half) @ W_fc^T, teams combine ----
    float wfcv[8];
#pragma unroll
    for (int o = 0; o < 2; ++o)
#pragma unroll
        for (int r = 0; r < 4; ++r)
            wfcv[o * 4 + r] = W_fc[o * HH + u + r];

    float p0 = hv[0]*wfcv[0] + hv[1]*wfcv[1] + hv[2]*wfcv[2] + hv[3]*wfcv[3];
    float p1 = hv[0]*wfcv[4] + hv[1]*wfcv[5] + hv[2]*wfcv[6] + hv[3]*wfcv[7];
    p0 += __shfl_xor(p0, 16, 64); p0 += __shfl_xor(p0, 32, 64);
    p1 += __shfl_xor(p1, 16, 64); p1 += __shfl_xor(p1, 32, 64);
    if (lg == 0) {
        atomicAdd(&outacc[lr * 2 + 0], p0);
        atomicAdd(&outacc[lr * 2 + 1], p1);
    }
    __syncthreads();
    if (tid < BC * 2) {
        int b2 = tid >> 1, o = tid & 1;
        float v = outacc[tid] + (rho == 0 ? b_fc[o] : 0.f);
        atomicAdd(&out[(size_t)(b0 + b2) * 2 + o], v);
    }
}

extern "C" void kernel_launch(void* const* d_in, const int* in_sizes, int n_in,
                              void* d_out, int out_size, void* d_ws, size_t ws_size,
                              hipStream_t stream) {
    const float* y_hist = (const float*)d_in[0];
    const float* h0     = (const float*)d_in[1];
    const float* c0     = (const float*)d_in[2];
    const float* W_ih   = (const float*)d_in[3];
    const float* W_hh   = (const float*)d_in[4];
    const float* b_ih   = (const float*)d_in[5];
    const float* b_hh   = (const float*)d_in[6];
    const float* W_fc   = (const float*)d_in[7];
    const float* b_fc   = (const float*)d_in[8];

    char* hx = (char*)d_ws;   // 256 blocks x 2 parities x 8 KB = 4 MB

    // Graph-safe per-launch init: zero tags (0 never matches a step tag),
    // zero out (atomicAdd epilogue).
    hipMemsetAsync(d_out, 0, (size_t)out_size * sizeof(float), stream);
    hipMemsetAsync(hx, 0, 256 * 2 * 8192, stream);

    lstm_team2<<<256, 512, 0, stream>>>(
        y_hist, h0, c0, W_ih, W_hh, b_ih, b_hh, W_fc, b_fc,
        (float*)d_out, hx);
}

// Round 8
// 665.242 us; speedup vs baseline: 4.3813x; 4.3813x over previous
//
#include <hip/hip_runtime.h>
#include <hip/hip_bf16.h>

// Single-CU-autonomous LSTM: 128 blocks x 512 threads, BC=16 batches/block.
// Full W_hh (1024x256 bf16 = 512 KB) per block: 6/8 tiles per wave in the
// unified VGPR/AGPR file (384 KB), 2/8 tiles in LDS (128 KB). No cross-block
// communication of any kind. x*w_x + bias folded in as a 9th MFMA K-step
// ([W | w_x | bias] @ [h; x; 1]). One barrier per step.

#define TT 256
#define HH 256
#define BC 16
#define NTH 512

typedef __attribute__((ext_vector_type(8))) short short8;
typedef __attribute__((ext_vector_type(4))) float floatx4;

__device__ __forceinline__ unsigned short f2bf(float f) {
    union { float f; unsigned u; } v; v.f = f;
    unsigned r = v.u + 0x7FFFu + ((v.u >> 16) & 1u);   // RNE, finite inputs only
    return (unsigned short)(r >> 16);
}
__device__ __forceinline__ float sigf(float x) {
    return __builtin_amdgcn_rcpf(1.f + __expf(-x));
}
__device__ __forceinline__ float tanh_(float x) {
    return 1.f - 2.f * __builtin_amdgcn_rcpf(__expf(2.f * x) + 1.f);
}

__global__ __attribute__((amdgpu_flat_work_group_size(512, 512),
                          amdgpu_waves_per_eu(2, 2)))
void lstm_onecu(
    const float* __restrict__ y_hist, const float* __restrict__ h0,
    const float* __restrict__ c0, const float* __restrict__ W_ih,
    const float* __restrict__ W_hh, const float* __restrict__ b_ih,
    const float* __restrict__ b_hh, const float* __restrict__ W_fc,
    const float* __restrict__ b_fc, float* __restrict__ out)
{
    // LDS budget (160 KB): W tiles 128K + h ping-pong 16K + x 8K + wxb 4K
    __shared__ __align__(16) char  WLDS[131072];   // [w][ti][s][lane] 16B frags
    __shared__ __align__(16) char  hb[2][8192];    // [b 16][hid 256] bf16, swz
    __shared__ unsigned short xw[TT * BC];         // bf16(x) [t][b]
    __shared__ unsigned wxb[8 * 8 * 16];           // {bias|wx} per (w,tau,lr)
    __shared__ float outacc[BC * 2];

    const int tid = threadIdx.x;
    const int w   = tid >> 6;        // wave 0..7: owns hidden [32w, 32w+32)
    const int l   = tid & 63;
    const int lr  = l & 15;          // batch lane (B/D col); A-row lane
    const int lg  = l >> 4;          // k-group 0..3
    const int b0  = blockIdx.x * BC;

    // ---- stage x -> bf16 [t][b] ----
    for (int idx = tid; idx < TT * BC; idx += NTH) {
        int bb = idx >> 8, t = idx & 255;
        xw[t * BC + bb] = f2bf(y_hist[(size_t)(b0 + bb) * TT + t]);
    }
    // ---- stage h0 -> bf16 swizzled LDS buf0 ----
    for (int idx = tid; idx < BC * 128; idx += NTH) {
        int bb = idx >> 7, d = idx & 127;
        const float* hp = &h0[(size_t)(b0 + bb) * HH + 2 * d];
        unsigned val = (unsigned)f2bf(hp[0]) | ((unsigned)f2bf(hp[1]) << 16);
        *(unsigned*)(hb[0] + bb * 512 + ((d * 4) ^ ((bb & 7) << 4))) = val;
    }
    if (tid < BC * 2) outacc[tid] = 0.f;

    // ---- c state: lane owns (batch lr, units 32w+16ch+4lg+r) ----
    float cc[2][4];
#pragma unroll
    for (int ch = 0; ch < 2; ++ch)
#pragma unroll
        for (int r = 0; r < 4; ++r)
            cc[ch][r] = c0[(size_t)(b0 + lr) * HH + 32 * w + 16 * ch + 4 * lg + r];

    // ---- W tiles: tau = ch*4 + gt; reg tiles tau 0..5, LDS tiles 6,7 ----
    short8 wfrag[48];
#pragma unroll
    for (int tau = 0; tau < 6; ++tau) {
        const int gt = tau & 3, ch = tau >> 2;
        const int row = 256 * gt + 32 * w + 16 * ch + lr;
#pragma unroll
        for (int s = 0; s < 8; ++s) {
            const float* p = &W_hh[(size_t)row * HH + 8 * lg + 32 * s];
            short8 f;
#pragma unroll
            for (int i = 0; i < 8; ++i) f[i] = (short)f2bf(p[i]);
            wfrag[tau * 8 + s] = f;
        }
    }
#pragma unroll
    for (int i = 0; i < 48; ++i)
        asm volatile("" : "+v"(wfrag[i]));

#pragma unroll
    for (int ti = 0; ti < 2; ++ti) {                 // tau 6,7: ch=1, gt=2+ti
        const int row = 256 * (2 + ti) + 32 * w + 16 + lr;
#pragma unroll
        for (int s = 0; s < 8; ++s) {
            const float* p = &W_hh[(size_t)row * HH + 8 * lg + 32 * s];
            short8 f;
#pragma unroll
            for (int i = 0; i < 8; ++i) f[i] = (short)f2bf(p[i]);
            *(short8*)(WLDS + w * 16384 + ti * 8192 + s * 1024 + l * 16) = f;
        }
    }
    // ---- wxb: per (w, tau, row=lr): lo16 = w_x, hi16 = bias ----
#pragma unroll
    for (int tau = 0; tau < 8; ++tau) {
        const int gt = tau & 3, ch = tau >> 2;
        const int row = 256 * gt + 32 * w + 16 * ch + lr;
        if (lg == 0)
            wxb[w * 128 + tau * 16 + lr] =
                (unsigned)f2bf(W_ih[row]) |
                ((unsigned)f2bf(b_ih[row] + b_hh[row]) << 16);
    }

    __syncthreads();

    const unsigned sw  = (unsigned)((lr & 7) << 4);
    const unsigned rdb = (unsigned)(lr * 512);
    const unsigned cwb = (unsigned)(64 * w + 8 * lg);   // write col base
    const char* wbase = WLDS + w * 16384 + l * 16;
    float hv[2][4];

#pragma unroll 1
    for (int t = 0; t < TT; ++t) {
        const char* rb = hb[t & 1];
        char* wbp = hb[(t + 1) & 1];

        floatx4 acc[8] = {};

#pragma unroll
        for (int s = 0; s < 8; ++s) {
            short8 bfr = *(const short8*)(rb + rdb +
                             (((unsigned)(16 * lg + 64 * s)) ^ sw));
#pragma unroll
            for (int tau = 0; tau < 6; ++tau)
                acc[tau] = __builtin_amdgcn_mfma_f32_16x16x32_bf16(
                               wfrag[tau * 8 + s], bfr, acc[tau], 0, 0, 0);
            short8 w6 = *(const short8*)(wbase + s * 1024);
            acc[6] = __builtin_amdgcn_mfma_f32_16x16x32_bf16(
                         w6, bfr, acc[6], 0, 0, 0);
            short8 w7 = *(const short8*)(wbase + 8192 + s * 1024);
            acc[7] = __builtin_amdgcn_mfma_f32_16x16x32_bf16(
                         w7, bfr, acc[7], 0, 0, 0);
        }

        // ---- 9th K-step: [w_x | bias] x [x; 1] (lg==0 lanes carry k=256,257)
        {
            unsigned xword = (lg == 0)
                ? ((0x3F80u << 16) | (unsigned)xw[t * BC + lr]) : 0u;
            short8 b8 = {(short)(xword & 0xFFFF), (short)(xword >> 16),
                         0, 0, 0, 0, 0, 0};
#pragma unroll
            for (int tau = 0; tau < 8; ++tau) {
                unsigned wv = (lg == 0) ? wxb[w * 128 + tau * 16 + lr] : 0u;
                short8 a8 = {(short)(wv & 0xFFFF), (short)(wv >> 16),
                             0, 0, 0, 0, 0, 0};
                acc[tau] = __builtin_amdgcn_mfma_f32_16x16x32_bf16(
                               a8, b8, acc[tau], 0, 0, 0);
            }
        }

        // ---- gates -> c,h ----
#pragma unroll
        for (int ch = 0; ch < 2; ++ch) {
#pragma unroll
            for (int r = 0; r < 4; ++r) {
                float iv = sigf(acc[ch * 4 + 0][r]);
                float fv = sigf(acc[ch * 4 + 1][r]);
                float gv = tanh_(acc[ch * 4 + 2][r]);
                float ov = sigf(acc[ch * 4 + 3][r]);
                float c2 = fmaf(fv, cc[ch][r], iv * gv);
                cc[ch][r] = c2;
                hv[ch][r] = ov * tanh_(c2);
            }
            unsigned lo = (unsigned)f2bf(hv[ch][0]) |
                          ((unsigned)f2bf(hv[ch][1]) << 16);
            unsigned hi = (unsigned)f2bf(hv[ch][2]) |
                          ((unsigned)f2bf(hv[ch][3]) << 16);
            uint2 pk; pk.x = lo; pk.y = hi;
            *(uint2*)(wbp + rdb + (((unsigned)(cwb + 32 * ch)) ^ sw)) = pk;
        }

        __syncthreads();
    }

    // ---- epilogue: out = h_T @ W_fc^T + b_fc (block owns its batches) ----
    float p0 = 0.f, p1 = 0.f;
#pragma unroll
    for (int ch = 0; ch < 2; ++ch)
#pragma unroll
        for (int r = 0; r < 4; ++r) {
            const int u = 32 * w + 16 * ch + 4 * lg + r;
            p0 = fmaf(hv[ch][r], W_fc[u],      p0);
            p1 = fmaf(hv[ch][r], W_fc[HH + u], p1);
        }
    p0 += __shfl_xor(p0, 16, 64); p0 += __shfl_xor(p0, 32, 64);
    p1 += __shfl_xor(p1, 16, 64); p1 += __shfl_xor(p1, 32, 64);
    if (lg == 0) {
        atomicAdd(&outacc[lr * 2 + 0], p0);
        atomicAdd(&outacc[lr * 2 + 1], p1);
    }
    __syncthreads();
    if (tid < BC * 2) {
        int bb = tid >> 1, o = tid & 1;
        out[(size_t)(b0 + bb) * 2 + o] = outacc[tid] + b_fc[o];
    }
}

extern "C" void kernel_launch(void* const* d_in, const int* in_sizes, int n_in,
                              void* d_out, int out_size, void* d_ws, size_t ws_size,
                              hipStream_t stream) {
    const float* y_hist = (const float*)d_in[0];
    const float* h0     = (const float*)d_in[1];
    const float* c0     = (const float*)d_in[2];
    const float* W_ih   = (const float*)d_in[3];
    const float* W_hh   = (const float*)d_in[4];
    const float* b_ih   = (const float*)d_in[5];
    const float* b_hh   = (const float*)d_in[6];
    const float* W_fc   = (const float*)d_in[7];
    const float* b_fc   = (const float*)d_in[8];

    lstm_onecu<<<2048 / BC, NTH, 0, stream>>>(
        y_hist, h0, c0, W_ih, W_hh, b_ih, b_hh, W_fc, b_fc, (float*)d_out);
}